// Round 11
// baseline (188.591 us; speedup 1.0000x reference)
//
#include <hip/hip_runtime.h>

#define NTOK 4096

typedef __attribute__((ext_vector_type(8))) short short8;
typedef __attribute__((ext_vector_type(4))) float f32x4;
typedef __attribute__((ext_vector_type(4))) unsigned int uint4v;

__device__ __forceinline__ unsigned short f2bf(float f) {
    unsigned u = __float_as_uint(f);
    u += 0x7fffu + ((u >> 16) & 1u);   // RNE; inputs finite
    return (unsigned short)(u >> 16);
}

__device__ __forceinline__ float bf2f(unsigned short h) {
    return __uint_as_float((unsigned)h << 16);
}

// pack two fp32 -> bf16 pair (truncation) in one v_perm_b32
__device__ __forceinline__ unsigned int pk2(float lo, float hi) {
    return __builtin_amdgcn_perm(__float_as_uint(hi), __float_as_uint(lo), 0x07060302u);
}

// ---------------- projection, ctx read ONCE -----------------------------------
// grid (64 n-tiles, 2 b, 2 z), 512 thr.
// z=0: k+v from ctx — thread (nn=tid&63, osub=tid>>6) computes v channels
//      [osub*8,+8) and k channel osub over the same 64 ctx values.
// z=1: q from x — thread computes q channel osub (log2e folded).
//      Block (0,0,z=1) zeros the 128 merge counters (proj retires before attn).
// Outputs: qbf/kbf [b][n][8] bf16; vtp tile-contiguous (R9 verified layout).
__global__ __launch_bounds__(512) void proj2(
    const float* __restrict__ x, const float* __restrict__ ctx,
    const float* __restrict__ Wq, const float* __restrict__ bq,
    const float* __restrict__ Wk, const float* __restrict__ bk,
    const float* __restrict__ Wv, const float* __restrict__ bv,
    unsigned short* __restrict__ qbf, unsigned short* __restrict__ kbf,
    unsigned short* __restrict__ vtp, int* __restrict__ cnt)
{
    __shared__ float sWv[64 * 64];
    __shared__ float sWk[8 * 64];
    __shared__ float sbv[64], sbk[8];

    int tid = threadIdx.x;
    int nt  = blockIdx.x;
    int b   = blockIdx.y;
    int z   = blockIdx.z;
    int n0  = nt * 64;
    int nn  = tid & 63;
    int osub = tid >> 6;            // 0..7

    if (z == 1) {
        // ---- q slice (reads x only)
        if (nt == 0 && b == 0 && tid < 128) cnt[tid] = 0;
        if (tid < 512) { if (tid < 512) sWk[0] = sWk[0]; }  // no-op keep shape
        // reuse sWk storage for Wq
        for (int i = tid; i < 512; i += 512) sWk[i] = Wq[i];
        if (tid < 8) sbk[tid] = bq[tid];
        __syncthreads();
        const float* xp = x + (size_t)b * 64 * NTOK + n0 + nn;
        float a = sbk[osub];
#pragma unroll 16
        for (int c = 0; c < 64; ++c)
            a += sWk[osub * 64 + c] * xp[(size_t)c * NTOK];
        qbf[((size_t)b * NTOK + n0 + nn) * 8 + osub] = f2bf(a * 1.4426950408889634f);
        return;
    }

    // ---- kv slice (reads ctx once)
    for (int i = tid; i < 4096; i += 512) sWv[i] = Wv[i];
    if (tid < 512) sWk[tid] = Wk[tid];
    if (tid < 64) sbv[tid] = bv[tid];
    else if (tid >= 64 && tid < 72) sbk[tid - 64] = bk[tid - 64];
    __syncthreads();

    const float* cp = ctx + (size_t)b * 64 * NTOK + n0 + nn;
    float av[8];
#pragma unroll
    for (int j = 0; j < 8; ++j) av[j] = sbv[osub * 8 + j];
    float ak = sbk[osub];
#pragma unroll 8
    for (int c = 0; c < 64; ++c) {
        float v = cp[(size_t)c * NTOK];
        ak += sWk[osub * 64 + c] * v;
#pragma unroll
        for (int j = 0; j < 8; ++j)
            av[j] += sWv[(osub * 8 + j) * 64 + c] * v;
    }

    kbf[((size_t)b * NTOK + n0 + nn) * 8 + osub] = f2bf(ak);

    int m  = n0 + nn;
    int T  = m >> 5;
    int mm = m & 31;
    int p  = ((mm >> 2) & 3) * 8 + (mm >> 4) * 4 + (mm & 3);   // verified perm
    int qd = p >> 3, j2 = p & 7;
    unsigned short* vB = vtp + (size_t)b * 64 * NTOK;
#pragma unroll
    for (int j = 0; j < 8; ++j) {
        int c    = osub * 8 + j;
        int ctv  = c >> 4;
        int lanev = (c & 15) + 16 * qd;
        vB[(((size_t)T * 4 + ctv) * 64 + lanev) * 8 + j2] = f2bf(av[j]);
    }
}

// ---------------- fused flash attention + last-block merge -------------------
// Core identical to verified attn8 (R9): block (64-row nt, b, m-eighth qz),
// 256 thr = 4 waves; wave scans 128 m; V frags 1 KB bursts reused x4 across
// n-groups; S via mfma_16x16x32_bf16 (K slots 8..31 zero); S D-regs feed PV
// B-frags under vtp layout; v_exp2 (q carries log2e); no max-subtraction.
// New: after writing its partial, each block does a device-scope ACQ_REL
// fetch_add on cnt[b*64+nt]; the 8th arrival merges all partials + residual,
// eliminating the mergeq dispatch (guide G16 device-scope atomics).
__global__ __launch_bounds__(256, 2) void attn9(
    const unsigned short* __restrict__ qbf, const unsigned short* __restrict__ kbf,
    const unsigned short* __restrict__ vtp,
    unsigned short* __restrict__ partO, float* __restrict__ partL,
    int* __restrict__ cnt, const float* __restrict__ x,
    const float* __restrict__ gamma, float* __restrict__ out)
{
    __shared__ float sOc[4][16][68];
    __shared__ float sL[4][64];
    __shared__ int sOld;

    int tid  = threadIdx.x;
    int w    = tid >> 6, lane = tid & 63;
    int n    = lane & 15, quad = lane >> 4;
    int nt   = blockIdx.x;
    int b    = blockIdx.y;
    int qz   = blockIdx.z;           // 0..7
    int n0   = nt * 64;

    const f32x4 z4 = {0.f, 0.f, 0.f, 0.f};
    const short8 z8 = {0, 0, 0, 0, 0, 0, 0, 0};

    short8 bq[4];
#pragma unroll
    for (int g = 0; g < 4; ++g)
        bq[g] = (quad == 0)
            ? *(const short8*)&qbf[((size_t)b * NTOK + n0 + g * 16 + n) * 8]
            : z8;

    const unsigned short* kb = kbf + (size_t)b * NTOK * 8;
    const unsigned short* vb = vtp + (size_t)b * 64 * NTOK;
    int mwbase = qz * 512 + w * 128;

    f32x4 acc[4][4];
#pragma unroll
    for (int g = 0; g < 4; ++g)
#pragma unroll
        for (int ct = 0; ct < 4; ++ct) acc[g][ct] = z4;
    float lsum[4] = {0.f, 0.f, 0.f, 0.f};

    for (int h = 0; h < 2; ++h) {
        int m0 = mwbase + h * 64;
        int Tb = m0 >> 5;

        short8 kf0 = (quad == 0) ? *(const short8*)&kb[(size_t)(m0 + 0 * 16 + n) * 8] : z8;
        short8 kf1 = (quad == 0) ? *(const short8*)&kb[(size_t)(m0 + 1 * 16 + n) * 8] : z8;
        short8 kf2 = (quad == 0) ? *(const short8*)&kb[(size_t)(m0 + 2 * 16 + n) * 8] : z8;
        short8 kf3 = (quad == 0) ? *(const short8*)&kb[(size_t)(m0 + 3 * 16 + n) * 8] : z8;

        short8 af[2][4];
#pragma unroll
        for (int s = 0; s < 2; ++s)
#pragma unroll
            for (int ct = 0; ct < 4; ++ct)
                af[s][ct] = *(const short8*)&vb[(((size_t)(Tb + s) * 4 + ct) * 64 + lane) * 8];

#pragma unroll
        for (int g = 0; g < 4; ++g) {
            f32x4 sa0 = __builtin_amdgcn_mfma_f32_16x16x32_bf16(kf0, bq[g], z4, 0, 0, 0);
            f32x4 sa1 = __builtin_amdgcn_mfma_f32_16x16x32_bf16(kf1, bq[g], z4, 0, 0, 0);
            f32x4 sa2 = __builtin_amdgcn_mfma_f32_16x16x32_bf16(kf2, bq[g], z4, 0, 0, 0);
            f32x4 sa3 = __builtin_amdgcn_mfma_f32_16x16x32_bf16(kf3, bq[g], z4, 0, 0, 0);

            float e00 = __builtin_amdgcn_exp2f(sa0[0]), e01 = __builtin_amdgcn_exp2f(sa0[1]);
            float e02 = __builtin_amdgcn_exp2f(sa0[2]), e03 = __builtin_amdgcn_exp2f(sa0[3]);
            float e10 = __builtin_amdgcn_exp2f(sa1[0]), e11 = __builtin_amdgcn_exp2f(sa1[1]);
            float e12 = __builtin_amdgcn_exp2f(sa1[2]), e13 = __builtin_amdgcn_exp2f(sa1[3]);
            float e20 = __builtin_amdgcn_exp2f(sa2[0]), e21 = __builtin_amdgcn_exp2f(sa2[1]);
            float e22 = __builtin_amdgcn_exp2f(sa2[2]), e23 = __builtin_amdgcn_exp2f(sa2[3]);
            float e30 = __builtin_amdgcn_exp2f(sa3[0]), e31 = __builtin_amdgcn_exp2f(sa3[1]);
            float e32 = __builtin_amdgcn_exp2f(sa3[2]), e33 = __builtin_amdgcn_exp2f(sa3[3]);
            lsum[g] += ((e00 + e01) + (e02 + e03)) + ((e10 + e11) + (e12 + e13))
                     + ((e20 + e21) + (e22 + e23)) + ((e30 + e31) + (e32 + e33));

            uint4v t0, t1;
            t0[0] = pk2(e00, e01); t0[1] = pk2(e02, e03);
            t0[2] = pk2(e10, e11); t0[3] = pk2(e12, e13);
            t1[0] = pk2(e20, e21); t1[1] = pk2(e22, e23);
            t1[2] = pk2(e30, e31); t1[3] = pk2(e32, e33);
            short8 pf0 = __builtin_bit_cast(short8, t0);
            short8 pf1 = __builtin_bit_cast(short8, t1);

            acc[g][0] = __builtin_amdgcn_mfma_f32_16x16x32_bf16(af[0][0], pf0, acc[g][0], 0, 0, 0);
            acc[g][1] = __builtin_amdgcn_mfma_f32_16x16x32_bf16(af[0][1], pf0, acc[g][1], 0, 0, 0);
            acc[g][2] = __builtin_amdgcn_mfma_f32_16x16x32_bf16(af[0][2], pf0, acc[g][2], 0, 0, 0);
            acc[g][3] = __builtin_amdgcn_mfma_f32_16x16x32_bf16(af[0][3], pf0, acc[g][3], 0, 0, 0);
            acc[g][0] = __builtin_amdgcn_mfma_f32_16x16x32_bf16(af[1][0], pf1, acc[g][0], 0, 0, 0);
            acc[g][1] = __builtin_amdgcn_mfma_f32_16x16x32_bf16(af[1][1], pf1, acc[g][1], 0, 0, 0);
            acc[g][2] = __builtin_amdgcn_mfma_f32_16x16x32_bf16(af[1][2], pf1, acc[g][2], 0, 0, 0);
            acc[g][3] = __builtin_amdgcn_mfma_f32_16x16x32_bf16(af[1][3], pf1, acc[g][3], 0, 0, 0);
        }
    }

    // ---- softmax denominators
#pragma unroll
    for (int g = 0; g < 4; ++g) {
        float l = lsum[g];
        l += __shfl_xor(l, 16);
        l += __shfl_xor(l, 32);
        if (lane < 16) sL[w][g * 16 + n] = l;
    }

    unsigned short* pO = partO + ((size_t)((b * 64 + nt) * 8 + qz)) * 4096;
    float*          pL = partL + ((size_t)((b * 64 + nt) * 8 + qz)) * 64;

    // ---- cross-wave reduce in 4 ct-chunks
#pragma unroll
    for (int ct = 0; ct < 4; ++ct) {
        if (ct) __syncthreads();
#pragma unroll
        for (int g = 0; g < 4; ++g)
#pragma unroll
            for (int r = 0; r < 4; ++r)
                sOc[w][quad * 4 + r][g * 16 + n] = acc[g][ct][r];
        __syncthreads();
        for (int i = tid; i < 1024; i += 256) {
            int c16 = i >> 6, nn2 = i & 63;
            float s = sOc[0][c16][nn2] + sOc[1][c16][nn2]
                    + sOc[2][c16][nn2] + sOc[3][c16][nn2];
            pO[ct * 1024 + i] = f2bf(s);
        }
    }
    if (tid < 64)
        pL[tid] = sL[0][tid] + sL[1][tid] + sL[2][tid] + sL[3][tid];

    // ---- last arrival merges all 8 partials (device-scope ACQ_REL)
    __threadfence();
    if (tid == 0)
        sOld = __hip_atomic_fetch_add(&cnt[b * 64 + nt], 1,
                                      __ATOMIC_ACQ_REL, __HIP_MEMORY_SCOPE_AGENT);
    __syncthreads();
    if (sOld != 7) return;

    const unsigned short* pOb = partO + ((size_t)((b * 64 + nt) * 8)) * 4096;
    const float*          pLb = partL + ((size_t)((b * 64 + nt) * 8)) * 64;
    float gm = gamma[0];
    int c = tid >> 2;
    int j = tid & 3;
#pragma unroll
    for (int nq = 0; nq < 4; ++nq) {
        int ns = j * 16 + nq * 4;
        float4 o = {0.f, 0.f, 0.f, 0.f};
        float4 L = {0.f, 0.f, 0.f, 0.f};
#pragma unroll
        for (int q8 = 0; q8 < 8; ++q8) {
            ushort4 ov = *(const ushort4*)&pOb[q8 * 4096 + c * 64 + ns];
            float4  lv = *(const float4*)&pLb[q8 * 64 + ns];
            o.x += bf2f(ov.x); o.y += bf2f(ov.y);
            o.z += bf2f(ov.z); o.w += bf2f(ov.w);
            L.x += lv.x; L.y += lv.y; L.z += lv.z; L.w += lv.w;
        }
        size_t ob = ((size_t)b * 64 + c) * NTOK + nt * 64 + ns;
        float4 xv = *(const float4*)&x[ob];
        float4 res;
        res.x = gm * (o.x / L.x) + xv.x;
        res.y = gm * (o.y / L.y) + xv.y;
        res.z = gm * (o.z / L.z) + xv.z;
        res.w = gm * (o.w / L.w) + xv.w;
        *(float4*)&out[ob] = res;
    }
}

extern "C" void kernel_launch(void* const* d_in, const int* in_sizes, int n_in,
                              void* d_out, int out_size, void* d_ws, size_t ws_size,
                              hipStream_t stream) {
    const float* x     = (const float*)d_in[0];
    const float* ctx   = (const float*)d_in[1];
    const float* Wq    = (const float*)d_in[2];
    const float* bq    = (const float*)d_in[3];
    const float* Wk    = (const float*)d_in[4];
    const float* bk    = (const float*)d_in[5];
    const float* Wv    = (const float*)d_in[6];
    const float* bv    = (const float*)d_in[7];
    const float* gamma = (const float*)d_in[8];
    float* out = (float*)d_out;

    unsigned short* qbf   = (unsigned short*)d_ws;        // [2][4096][8]
    unsigned short* kbf   = qbf + 2 * NTOK * 8;           // [2][4096][8]
    unsigned short* vtp   = kbf + 2 * NTOK * 8;           // [2][128T][4ct][512]
    unsigned short* partO = vtp + 2 * 64 * NTOK;          // [2*64*8][4096] bf16
    float*          partL = (float*)(partO + (size_t)2 * 64 * 8 * 4096); // [1024][64]
    int*            cnt   = (int*)(partL + 2 * 64 * 8 * 64);             // [128]

    proj2<<<dim3(64, 2, 2), 512, 0, stream>>>(x, ctx, Wq, bq, Wk, bk, Wv, bv,
                                              qbf, kbf, vtp, cnt);
    attn9<<<dim3(NTOK / 64, 2, 8), 256, 0, stream>>>(qbf, kbf, vtp, partO, partL,
                                                     cnt, x, gamma, out);
}

// Round 12
// 99.409 us; speedup vs baseline: 1.8971x; 1.8971x over previous
//
#include <hip/hip_runtime.h>

#define NTOK 4096

typedef __attribute__((ext_vector_type(8))) short short8;
typedef __attribute__((ext_vector_type(4))) float f32x4;
typedef __attribute__((ext_vector_type(4))) unsigned int uint4v;

__device__ __forceinline__ unsigned short f2bf(float f) {
    unsigned u = __float_as_uint(f);
    u += 0x7fffu + ((u >> 16) & 1u);   // RNE; inputs finite
    return (unsigned short)(u >> 16);
}

__device__ __forceinline__ float bf2f(unsigned short h) {
    return __uint_as_float((unsigned)h << 16);
}

// pack two fp32 -> bf16 pair (truncation) in one v_perm_b32
__device__ __forceinline__ unsigned int pk2(float lo, float hi) {
    return __builtin_amdgcn_perm(__float_as_uint(hi), __float_as_uint(lo), 0x07060302u);
}

// ---------------- projection, ctx read ONCE (R11-verified, cnt removed) ------
// grid (64 n-tiles, 2 b, 2 z), 512 thr.
// z=0: k+v from ctx — thread (nn, osub) computes v channels [osub*8,+8) and
//      k channel osub over the same 64 ctx values (ctx read once: 17 MB).
// z=1: q from x (log2e folded).
// Outputs: qbf/kbf [b][n][8] bf16; vtp tile-contiguous (R9 verified layout).
__global__ __launch_bounds__(512) void proj2(
    const float* __restrict__ x, const float* __restrict__ ctx,
    const float* __restrict__ Wq, const float* __restrict__ bq,
    const float* __restrict__ Wk, const float* __restrict__ bk,
    const float* __restrict__ Wv, const float* __restrict__ bv,
    unsigned short* __restrict__ qbf, unsigned short* __restrict__ kbf,
    unsigned short* __restrict__ vtp)
{
    __shared__ float sWv[64 * 64];
    __shared__ float sWk[8 * 64];
    __shared__ float sbv[64], sbk[8];

    int tid = threadIdx.x;
    int nt  = blockIdx.x;
    int b   = blockIdx.y;
    int z   = blockIdx.z;
    int n0  = nt * 64;
    int nn  = tid & 63;
    int osub = tid >> 6;            // 0..7

    if (z == 1) {
        // ---- q slice (reads x only); reuse sWk storage for Wq
        for (int i = tid; i < 512; i += 512) sWk[i] = Wq[i];
        if (tid < 8) sbk[tid] = bq[tid];
        __syncthreads();
        const float* xp = x + (size_t)b * 64 * NTOK + n0 + nn;
        float a = sbk[osub];
#pragma unroll 16
        for (int c = 0; c < 64; ++c)
            a += sWk[osub * 64 + c] * xp[(size_t)c * NTOK];
        qbf[((size_t)b * NTOK + n0 + nn) * 8 + osub] = f2bf(a * 1.4426950408889634f);
        return;
    }

    // ---- kv slice (reads ctx once)
    for (int i = tid; i < 4096; i += 512) sWv[i] = Wv[i];
    if (tid < 512) sWk[tid] = Wk[tid];
    if (tid < 64) sbv[tid] = bv[tid];
    else if (tid >= 64 && tid < 72) sbk[tid - 64] = bk[tid - 64];
    __syncthreads();

    const float* cp = ctx + (size_t)b * 64 * NTOK + n0 + nn;
    float av[8];
#pragma unroll
    for (int j = 0; j < 8; ++j) av[j] = sbv[osub * 8 + j];
    float ak = sbk[osub];
#pragma unroll 8
    for (int c = 0; c < 64; ++c) {
        float v = cp[(size_t)c * NTOK];
        ak += sWk[osub * 64 + c] * v;
#pragma unroll
        for (int j = 0; j < 8; ++j)
            av[j] += sWv[(osub * 8 + j) * 64 + c] * v;
    }

    kbf[((size_t)b * NTOK + n0 + nn) * 8 + osub] = f2bf(ak);

    int m  = n0 + nn;
    int T  = m >> 5;
    int mm = m & 31;
    int p  = ((mm >> 2) & 3) * 8 + (mm >> 4) * 4 + (mm & 3);   // verified perm
    int qd = p >> 3, j2 = p & 7;
    unsigned short* vB = vtp + (size_t)b * 64 * NTOK;
#pragma unroll
    for (int j = 0; j < 8; ++j) {
        int c    = osub * 8 + j;
        int ctv  = c >> 4;
        int lanev = (c & 15) + 16 * qd;
        vB[(((size_t)T * 4 + ctv) * 64 + lanev) * 8 + j2] = f2bf(av[j]);
    }
}

// ---------------- fused flash attention (R9 champion, verbatim) --------------
// block: (64-row n-tile nt, b, m-eighth qz), 256 thr = 4 waves.
// wave w owns m in [qz*512 + w*128, +128), 2 halves of 64 m.
// V frags 1 KB contiguous bursts, reused x4 across n-groups; S via
// mfma_16x16x32_bf16 (K slots 8..31 zero, exec-masked quad-0 loads); S D-regs
// feed PV B-frags under the vtp tile layout; native v_exp2 (q carries log2e);
// no max-subtraction (energies bounded, R3-R11). Partial O bf16 + L fp32 to
// ws; mergeq finishes. NO device-scope fences/atomics on the hot path (R11
// lesson: 2048 agent-scope releases throttled the chip 4.6x).
__global__ __launch_bounds__(256, 2) void attn8(
    const unsigned short* __restrict__ qbf, const unsigned short* __restrict__ kbf,
    const unsigned short* __restrict__ vtp,
    unsigned short* __restrict__ partO, float* __restrict__ partL)
{
    __shared__ float sOc[4][16][68];  // ct-chunk: [wave][c-sub 16][n 64]
    __shared__ float sL[4][64];

    int tid  = threadIdx.x;
    int w    = tid >> 6, lane = tid & 63;
    int n    = lane & 15, quad = lane >> 4;
    int nt   = blockIdx.x;
    int b    = blockIdx.y;
    int qz   = blockIdx.z;           // 0..7
    int n0   = nt * 64;

    const f32x4 z4 = {0.f, 0.f, 0.f, 0.f};
    const short8 z8 = {0, 0, 0, 0, 0, 0, 0, 0};

    short8 bq[4];
#pragma unroll
    for (int g = 0; g < 4; ++g)
        bq[g] = (quad == 0)
            ? *(const short8*)&qbf[((size_t)b * NTOK + n0 + g * 16 + n) * 8]
            : z8;

    const unsigned short* kb = kbf + (size_t)b * NTOK * 8;
    const unsigned short* vb = vtp + (size_t)b * 64 * NTOK;
    int mwbase = qz * 512 + w * 128;

    f32x4 acc[4][4];
#pragma unroll
    for (int g = 0; g < 4; ++g)
#pragma unroll
        for (int ct = 0; ct < 4; ++ct) acc[g][ct] = z4;
    float lsum[4] = {0.f, 0.f, 0.f, 0.f};

    for (int h = 0; h < 2; ++h) {
        int m0 = mwbase + h * 64;
        int Tb = m0 >> 5;             // two 32-m groups: Tb, Tb+1

        short8 kf0 = (quad == 0) ? *(const short8*)&kb[(size_t)(m0 + 0 * 16 + n) * 8] : z8;
        short8 kf1 = (quad == 0) ? *(const short8*)&kb[(size_t)(m0 + 1 * 16 + n) * 8] : z8;
        short8 kf2 = (quad == 0) ? *(const short8*)&kb[(size_t)(m0 + 2 * 16 + n) * 8] : z8;
        short8 kf3 = (quad == 0) ? *(const short8*)&kb[(size_t)(m0 + 3 * 16 + n) * 8] : z8;

        // V fragments: 1 KB contiguous per load (lane-indexed tile)
        short8 af[2][4];
#pragma unroll
        for (int s = 0; s < 2; ++s)
#pragma unroll
            for (int ct = 0; ct < 4; ++ct)
                af[s][ct] = *(const short8*)&vb[(((size_t)(Tb + s) * 4 + ct) * 64 + lane) * 8];

#pragma unroll
        for (int g = 0; g < 4; ++g) {
            f32x4 sa0 = __builtin_amdgcn_mfma_f32_16x16x32_bf16(kf0, bq[g], z4, 0, 0, 0);
            f32x4 sa1 = __builtin_amdgcn_mfma_f32_16x16x32_bf16(kf1, bq[g], z4, 0, 0, 0);
            f32x4 sa2 = __builtin_amdgcn_mfma_f32_16x16x32_bf16(kf2, bq[g], z4, 0, 0, 0);
            f32x4 sa3 = __builtin_amdgcn_mfma_f32_16x16x32_bf16(kf3, bq[g], z4, 0, 0, 0);

            float e00 = __builtin_amdgcn_exp2f(sa0[0]), e01 = __builtin_amdgcn_exp2f(sa0[1]);
            float e02 = __builtin_amdgcn_exp2f(sa0[2]), e03 = __builtin_amdgcn_exp2f(sa0[3]);
            float e10 = __builtin_amdgcn_exp2f(sa1[0]), e11 = __builtin_amdgcn_exp2f(sa1[1]);
            float e12 = __builtin_amdgcn_exp2f(sa1[2]), e13 = __builtin_amdgcn_exp2f(sa1[3]);
            float e20 = __builtin_amdgcn_exp2f(sa2[0]), e21 = __builtin_amdgcn_exp2f(sa2[1]);
            float e22 = __builtin_amdgcn_exp2f(sa2[2]), e23 = __builtin_amdgcn_exp2f(sa2[3]);
            float e30 = __builtin_amdgcn_exp2f(sa3[0]), e31 = __builtin_amdgcn_exp2f(sa3[1]);
            float e32 = __builtin_amdgcn_exp2f(sa3[2]), e33 = __builtin_amdgcn_exp2f(sa3[3]);
            lsum[g] += ((e00 + e01) + (e02 + e03)) + ((e10 + e11) + (e12 + e13))
                     + ((e20 + e21) + (e22 + e23)) + ((e30 + e31) + (e32 + e33));

            uint4v t0, t1;
            t0[0] = pk2(e00, e01); t0[1] = pk2(e02, e03);
            t0[2] = pk2(e10, e11); t0[3] = pk2(e12, e13);
            t1[0] = pk2(e20, e21); t1[1] = pk2(e22, e23);
            t1[2] = pk2(e30, e31); t1[3] = pk2(e32, e33);
            short8 pf0 = __builtin_bit_cast(short8, t0);
            short8 pf1 = __builtin_bit_cast(short8, t1);

            acc[g][0] = __builtin_amdgcn_mfma_f32_16x16x32_bf16(af[0][0], pf0, acc[g][0], 0, 0, 0);
            acc[g][1] = __builtin_amdgcn_mfma_f32_16x16x32_bf16(af[0][1], pf0, acc[g][1], 0, 0, 0);
            acc[g][2] = __builtin_amdgcn_mfma_f32_16x16x32_bf16(af[0][2], pf0, acc[g][2], 0, 0, 0);
            acc[g][3] = __builtin_amdgcn_mfma_f32_16x16x32_bf16(af[0][3], pf0, acc[g][3], 0, 0, 0);
            acc[g][0] = __builtin_amdgcn_mfma_f32_16x16x32_bf16(af[1][0], pf1, acc[g][0], 0, 0, 0);
            acc[g][1] = __builtin_amdgcn_mfma_f32_16x16x32_bf16(af[1][1], pf1, acc[g][1], 0, 0, 0);
            acc[g][2] = __builtin_amdgcn_mfma_f32_16x16x32_bf16(af[1][2], pf1, acc[g][2], 0, 0, 0);
            acc[g][3] = __builtin_amdgcn_mfma_f32_16x16x32_bf16(af[1][3], pf1, acc[g][3], 0, 0, 0);
        }
    }

    // ---- epilogue: softmax denominators
#pragma unroll
    for (int g = 0; g < 4; ++g) {
        float l = lsum[g];
        l += __shfl_xor(l, 16);
        l += __shfl_xor(l, 32);
        if (lane < 16) sL[w][g * 16 + n] = l;
    }

    unsigned short* pO = partO + ((size_t)((b * 64 + nt) * 8 + qz)) * 4096;
    float*          pL = partL + ((size_t)((b * 64 + nt) * 8 + qz)) * 64;

    // ---- cross-wave reduce in 4 ct-chunks (17 KB LDS)
#pragma unroll
    for (int ct = 0; ct < 4; ++ct) {
        if (ct) __syncthreads();
#pragma unroll
        for (int g = 0; g < 4; ++g)
#pragma unroll
            for (int r = 0; r < 4; ++r)
                sOc[w][quad * 4 + r][g * 16 + n] = acc[g][ct][r];
        __syncthreads();
        for (int i = tid; i < 1024; i += 256) {
            int c16 = i >> 6, nn2 = i & 63;
            float s = sOc[0][c16][nn2] + sOc[1][c16][nn2]
                    + sOc[2][c16][nn2] + sOc[3][c16][nn2];
            pO[ct * 1024 + i] = f2bf(s);
        }
    }
    if (tid < 64)
        pL[tid] = sL[0][tid] + sL[1][tid] + sL[2][tid] + sL[3][tid];
}

// ---------------- merge 8 m-eighths + residual (R9 verbatim) -----------------
__global__ __launch_bounds__(256) void mergeq(
    const unsigned short* __restrict__ partO, const float* __restrict__ partL,
    const float* __restrict__ x, const float* __restrict__ gamma,
    float* __restrict__ out)
{
    int tid = threadIdx.x;
    int nt  = blockIdx.x;
    int b   = blockIdx.y;
    int c   = tid >> 2;
    int j   = tid & 3;          // 16 n: j*16 .. j*16+15

    const unsigned short* pOb = partO + ((size_t)((b * 64 + nt) * 8)) * 4096;
    const float*          pLb = partL + ((size_t)((b * 64 + nt) * 8)) * 64;
    float g = gamma[0];
#pragma unroll
    for (int nq = 0; nq < 4; ++nq) {
        int ns = j * 16 + nq * 4;
        float4 o = {0.f, 0.f, 0.f, 0.f};
        float4 L = {0.f, 0.f, 0.f, 0.f};
#pragma unroll
        for (int qz = 0; qz < 8; ++qz) {
            ushort4 ov = *(const ushort4*)&pOb[qz * 4096 + c * 64 + ns];
            float4  lv = *(const float4*)&pLb[qz * 64 + ns];
            o.x += bf2f(ov.x); o.y += bf2f(ov.y);
            o.z += bf2f(ov.z); o.w += bf2f(ov.w);
            L.x += lv.x; L.y += lv.y; L.z += lv.z; L.w += lv.w;
        }
        size_t ob = ((size_t)b * 64 + c) * NTOK + nt * 64 + ns;
        float4 xv = *(const float4*)&x[ob];
        float4 res;
        res.x = g * (o.x / L.x) + xv.x;
        res.y = g * (o.y / L.y) + xv.y;
        res.z = g * (o.z / L.z) + xv.z;
        res.w = g * (o.w / L.w) + xv.w;
        *(float4*)&out[ob] = res;
    }
}

extern "C" void kernel_launch(void* const* d_in, const int* in_sizes, int n_in,
                              void* d_out, int out_size, void* d_ws, size_t ws_size,
                              hipStream_t stream) {
    const float* x     = (const float*)d_in[0];
    const float* ctx   = (const float*)d_in[1];
    const float* Wq    = (const float*)d_in[2];
    const float* bq    = (const float*)d_in[3];
    const float* Wk    = (const float*)d_in[4];
    const float* bk    = (const float*)d_in[5];
    const float* Wv    = (const float*)d_in[6];
    const float* bv    = (const float*)d_in[7];
    const float* gamma = (const float*)d_in[8];
    float* out = (float*)d_out;

    unsigned short* qbf   = (unsigned short*)d_ws;        // [2][4096][8]
    unsigned short* kbf   = qbf + 2 * NTOK * 8;           // [2][4096][8]
    unsigned short* vtp   = kbf + 2 * NTOK * 8;           // [2][128T][4ct][512]
    unsigned short* partO = vtp + 2 * 64 * NTOK;          // [2*64*8][4096] bf16
    float*          partL = (float*)(partO + (size_t)2 * 64 * 8 * 4096); // [1024][64]

    proj2<<<dim3(64, 2, 2), 512, 0, stream>>>(x, ctx, Wq, bq, Wk, bk, Wv, bv,
                                              qbf, kbf, vtp);
    attn8<<<dim3(NTOK / 64, 2, 8), 256, 0, stream>>>(qbf, kbf, vtp, partO, partL);
    mergeq<<<dim3(NTOK / 64, 2), 256, 0, stream>>>(partO, partL, x, gamma, out);
}

// Round 13
// 98.996 us; speedup vs baseline: 1.9050x; 1.0042x over previous
//
#include <hip/hip_runtime.h>

#define NTOK 4096

typedef __attribute__((ext_vector_type(8))) short short8;
typedef __attribute__((ext_vector_type(4))) float f32x4;
typedef long long i64;

__device__ __forceinline__ unsigned short f2bf(float f) {
    unsigned u = __float_as_uint(f);
    u += 0x7fffu + ((u >> 16) & 1u);   // RNE; inputs finite
    return (unsigned short)(u >> 16);
}

__device__ __forceinline__ float bf2f(unsigned short h) {
    return __uint_as_float((unsigned)h << 16);
}

__device__ __forceinline__ unsigned char f2fp8(float f) {
    return (unsigned char)(__builtin_amdgcn_cvt_pk_fp8_f32(f, f, 0, false) & 0xff);
}

// ---------------- projection, ctx read ONCE (R12 structure) ------------------
// z=0: k+v from ctx (ctx read once); z=1: q from x (log2e folded).
// qbf/kbf [b][n][8] bf16. vtp now FP8 e4m3, tile-contiguous: per (32-m group T,
// ct) a 512 B block, byte index ((T*4+ct)*64 + lane)*8 + j2 with the verified
// p-permutation (p = qd*8 + j2) of m within the group.
__global__ __launch_bounds__(512) void proj2(
    const float* __restrict__ x, const float* __restrict__ ctx,
    const float* __restrict__ Wq, const float* __restrict__ bq,
    const float* __restrict__ Wk, const float* __restrict__ bk,
    const float* __restrict__ Wv, const float* __restrict__ bv,
    unsigned short* __restrict__ qbf, unsigned short* __restrict__ kbf,
    unsigned char* __restrict__ vtp)
{
    __shared__ float sWv[64 * 64];
    __shared__ float sWk[8 * 64];
    __shared__ float sbv[64], sbk[8];

    int tid = threadIdx.x;
    int nt  = blockIdx.x;
    int b   = blockIdx.y;
    int z   = blockIdx.z;
    int n0  = nt * 64;
    int nn  = tid & 63;
    int osub = tid >> 6;            // 0..7

    if (z == 1) {
        for (int i = tid; i < 512; i += 512) sWk[i] = Wq[i];
        if (tid < 8) sbk[tid] = bq[tid];
        __syncthreads();
        const float* xp = x + (size_t)b * 64 * NTOK + n0 + nn;
        float a = sbk[osub];
#pragma unroll 16
        for (int c = 0; c < 64; ++c)
            a += sWk[osub * 64 + c] * xp[(size_t)c * NTOK];
        qbf[((size_t)b * NTOK + n0 + nn) * 8 + osub] = f2bf(a * 1.4426950408889634f);
        return;
    }

    for (int i = tid; i < 4096; i += 512) sWv[i] = Wv[i];
    if (tid < 512) sWk[tid] = Wk[tid];
    if (tid < 64) sbv[tid] = bv[tid];
    else if (tid >= 64 && tid < 72) sbk[tid - 64] = bk[tid - 64];
    __syncthreads();

    const float* cp = ctx + (size_t)b * 64 * NTOK + n0 + nn;
    float av[8];
#pragma unroll
    for (int j = 0; j < 8; ++j) av[j] = sbv[osub * 8 + j];
    float ak = sbk[osub];
#pragma unroll 8
    for (int c = 0; c < 64; ++c) {
        float v = cp[(size_t)c * NTOK];
        ak += sWk[osub * 64 + c] * v;
#pragma unroll
        for (int j = 0; j < 8; ++j)
            av[j] += sWv[(osub * 8 + j) * 64 + c] * v;
    }

    kbf[((size_t)b * NTOK + n0 + nn) * 8 + osub] = f2bf(ak);

    int m  = n0 + nn;
    int T  = m >> 5;
    int mm = m & 31;
    int p  = ((mm >> 2) & 3) * 8 + (mm >> 4) * 4 + (mm & 3);   // verified perm
    int qd = p >> 3, j2 = p & 7;
    unsigned char* vB = vtp + (size_t)b * 64 * NTOK;
#pragma unroll
    for (int j = 0; j < 8; ++j) {
        int c     = osub * 8 + j;
        int ctv   = c >> 4;
        int lanev = (c & 15) + 16 * qd;
        vB[(((size_t)T * 4 + ctv) * 64 + lanev) * 8 + j2] = f2fp8(av[j]);
    }
}

// ---------------- fused flash attention (R9 structure, PV in fp8) ------------
// block: (64-row nt, b, m-eighth qz), 256 thr = 4 waves; wave scans 128 m.
// S stays bf16 (energy precision dominates absmax). PV: P packed e4m3 via
// cvt_pk_fp8 (byte k = K slot quad*8+k — same slot order as verified bf16
// path), V fragments 512 B contiguous bursts (8 B/lane), reused x4 across
// n-groups; mfma_f32_16x16x32_fp8_fp8 (same shape -> same C/D layout).
// Scan traffic 75 -> 41 MB; af regs 32 -> 16 (VGPR ~105, safely under the 128
// cliff). No device-scope anything on the hot path (R11 lesson).
__global__ __launch_bounds__(256, 2) void attn10(
    const unsigned short* __restrict__ qbf, const unsigned short* __restrict__ kbf,
    const unsigned char* __restrict__ vtp,
    unsigned short* __restrict__ partO, float* __restrict__ partL)
{
    __shared__ float sOc[4][16][68];
    __shared__ float sL[4][64];

    int tid  = threadIdx.x;
    int w    = tid >> 6, lane = tid & 63;
    int n    = lane & 15, quad = lane >> 4;
    int nt   = blockIdx.x;
    int b    = blockIdx.y;
    int qz   = blockIdx.z;           // 0..7
    int n0   = nt * 64;

    const f32x4 z4 = {0.f, 0.f, 0.f, 0.f};
    const short8 z8 = {0, 0, 0, 0, 0, 0, 0, 0};

    short8 bq[4];
#pragma unroll
    for (int g = 0; g < 4; ++g)
        bq[g] = (quad == 0)
            ? *(const short8*)&qbf[((size_t)b * NTOK + n0 + g * 16 + n) * 8]
            : z8;

    const unsigned short* kb = kbf + (size_t)b * NTOK * 8;
    const unsigned char*  vb = vtp + (size_t)b * 64 * NTOK;
    int mwbase = qz * 512 + w * 128;

    f32x4 acc[4][4];
#pragma unroll
    for (int g = 0; g < 4; ++g)
#pragma unroll
        for (int ct = 0; ct < 4; ++ct) acc[g][ct] = z4;
    float lsum[4] = {0.f, 0.f, 0.f, 0.f};

#pragma unroll
    for (int h = 0; h < 2; ++h) {
        int m0 = mwbase + h * 64;
        int Tb = m0 >> 5;             // two 32-m groups: Tb, Tb+1

        short8 kf0 = (quad == 0) ? *(const short8*)&kb[(size_t)(m0 + 0 * 16 + n) * 8] : z8;
        short8 kf1 = (quad == 0) ? *(const short8*)&kb[(size_t)(m0 + 1 * 16 + n) * 8] : z8;
        short8 kf2 = (quad == 0) ? *(const short8*)&kb[(size_t)(m0 + 2 * 16 + n) * 8] : z8;
        short8 kf3 = (quad == 0) ? *(const short8*)&kb[(size_t)(m0 + 3 * 16 + n) * 8] : z8;

        // V fragments: fp8, 512 B contiguous per load (8 B/lane)
        i64 af[2][4];
#pragma unroll
        for (int s = 0; s < 2; ++s)
#pragma unroll
            for (int ct = 0; ct < 4; ++ct)
                af[s][ct] = *(const i64*)&vb[(((size_t)(Tb + s) * 4 + ct) * 64 + lane) * 8];

#pragma unroll
        for (int g = 0; g < 4; ++g) {
            f32x4 sa0 = __builtin_amdgcn_mfma_f32_16x16x32_bf16(kf0, bq[g], z4, 0, 0, 0);
            f32x4 sa1 = __builtin_amdgcn_mfma_f32_16x16x32_bf16(kf1, bq[g], z4, 0, 0, 0);
            f32x4 sa2 = __builtin_amdgcn_mfma_f32_16x16x32_bf16(kf2, bq[g], z4, 0, 0, 0);
            f32x4 sa3 = __builtin_amdgcn_mfma_f32_16x16x32_bf16(kf3, bq[g], z4, 0, 0, 0);

            float e00 = __builtin_amdgcn_exp2f(sa0[0]), e01 = __builtin_amdgcn_exp2f(sa0[1]);
            float e02 = __builtin_amdgcn_exp2f(sa0[2]), e03 = __builtin_amdgcn_exp2f(sa0[3]);
            float e10 = __builtin_amdgcn_exp2f(sa1[0]), e11 = __builtin_amdgcn_exp2f(sa1[1]);
            float e12 = __builtin_amdgcn_exp2f(sa1[2]), e13 = __builtin_amdgcn_exp2f(sa1[3]);
            float e20 = __builtin_amdgcn_exp2f(sa2[0]), e21 = __builtin_amdgcn_exp2f(sa2[1]);
            float e22 = __builtin_amdgcn_exp2f(sa2[2]), e23 = __builtin_amdgcn_exp2f(sa2[3]);
            float e30 = __builtin_amdgcn_exp2f(sa3[0]), e31 = __builtin_amdgcn_exp2f(sa3[1]);
            float e32 = __builtin_amdgcn_exp2f(sa3[2]), e33 = __builtin_amdgcn_exp2f(sa3[3]);
            lsum[g] += ((e00 + e01) + (e02 + e03)) + ((e10 + e11) + (e12 + e13))
                     + ((e20 + e21) + (e22 + e23)) + ((e30 + e31) + (e32 + e33));

            // pack P to fp8: byte k of i64 = K slot quad*8+k (same order as bf16 path)
            int p0lo = __builtin_amdgcn_cvt_pk_fp8_f32(e00, e01, 0, false);
            p0lo     = __builtin_amdgcn_cvt_pk_fp8_f32(e02, e03, p0lo, true);
            int p0hi = __builtin_amdgcn_cvt_pk_fp8_f32(e10, e11, 0, false);
            p0hi     = __builtin_amdgcn_cvt_pk_fp8_f32(e12, e13, p0hi, true);
            int p1lo = __builtin_amdgcn_cvt_pk_fp8_f32(e20, e21, 0, false);
            p1lo     = __builtin_amdgcn_cvt_pk_fp8_f32(e22, e23, p1lo, true);
            int p1hi = __builtin_amdgcn_cvt_pk_fp8_f32(e30, e31, 0, false);
            p1hi     = __builtin_amdgcn_cvt_pk_fp8_f32(e32, e33, p1hi, true);
            i64 pf0 = ((i64)(unsigned)p0hi << 32) | (unsigned)p0lo;
            i64 pf1 = ((i64)(unsigned)p1hi << 32) | (unsigned)p1lo;

            acc[g][0] = __builtin_amdgcn_mfma_f32_16x16x32_fp8_fp8(af[0][0], pf0, acc[g][0], 0, 0, 0);
            acc[g][1] = __builtin_amdgcn_mfma_f32_16x16x32_fp8_fp8(af[0][1], pf0, acc[g][1], 0, 0, 0);
            acc[g][2] = __builtin_amdgcn_mfma_f32_16x16x32_fp8_fp8(af[0][2], pf0, acc[g][2], 0, 0, 0);
            acc[g][3] = __builtin_amdgcn_mfma_f32_16x16x32_fp8_fp8(af[0][3], pf0, acc[g][3], 0, 0, 0);
            acc[g][0] = __builtin_amdgcn_mfma_f32_16x16x32_fp8_fp8(af[1][0], pf1, acc[g][0], 0, 0, 0);
            acc[g][1] = __builtin_amdgcn_mfma_f32_16x16x32_fp8_fp8(af[1][1], pf1, acc[g][1], 0, 0, 0);
            acc[g][2] = __builtin_amdgcn_mfma_f32_16x16x32_fp8_fp8(af[1][2], pf1, acc[g][2], 0, 0, 0);
            acc[g][3] = __builtin_amdgcn_mfma_f32_16x16x32_fp8_fp8(af[1][3], pf1, acc[g][3], 0, 0, 0);
        }
    }

    // ---- epilogue: softmax denominators
#pragma unroll
    for (int g = 0; g < 4; ++g) {
        float l = lsum[g];
        l += __shfl_xor(l, 16);
        l += __shfl_xor(l, 32);
        if (lane < 16) sL[w][g * 16 + n] = l;
    }

    unsigned short* pO = partO + ((size_t)((b * 64 + nt) * 8 + qz)) * 4096;
    float*          pL = partL + ((size_t)((b * 64 + nt) * 8 + qz)) * 64;

    // ---- cross-wave reduce in 4 ct-chunks (17 KB LDS)
#pragma unroll
    for (int ct = 0; ct < 4; ++ct) {
        if (ct) __syncthreads();
#pragma unroll
        for (int g = 0; g < 4; ++g)
#pragma unroll
            for (int r = 0; r < 4; ++r)
                sOc[w][quad * 4 + r][g * 16 + n] = acc[g][ct][r];
        __syncthreads();
        for (int i = tid; i < 1024; i += 256) {
            int c16 = i >> 6, nn2 = i & 63;
            float s = sOc[0][c16][nn2] + sOc[1][c16][nn2]
                    + sOc[2][c16][nn2] + sOc[3][c16][nn2];
            pO[ct * 1024 + i] = f2bf(s);
        }
    }
    if (tid < 64)
        pL[tid] = sL[0][tid] + sL[1][tid] + sL[2][tid] + sL[3][tid];
}

// ---------------- merge 8 m-eighths + residual (verbatim) --------------------
__global__ __launch_bounds__(256) void mergeq(
    const unsigned short* __restrict__ partO, const float* __restrict__ partL,
    const float* __restrict__ x, const float* __restrict__ gamma,
    float* __restrict__ out)
{
    int tid = threadIdx.x;
    int nt  = blockIdx.x;
    int b   = blockIdx.y;
    int c   = tid >> 2;
    int j   = tid & 3;

    const unsigned short* pOb = partO + ((size_t)((b * 64 + nt) * 8)) * 4096;
    const float*          pLb = partL + ((size_t)((b * 64 + nt) * 8)) * 64;
    float g = gamma[0];
#pragma unroll
    for (int nq = 0; nq < 4; ++nq) {
        int ns = j * 16 + nq * 4;
        float4 o = {0.f, 0.f, 0.f, 0.f};
        float4 L = {0.f, 0.f, 0.f, 0.f};
#pragma unroll
        for (int qz = 0; qz < 8; ++qz) {
            ushort4 ov = *(const ushort4*)&pOb[qz * 4096 + c * 64 + ns];
            float4  lv = *(const float4*)&pLb[qz * 64 + ns];
            o.x += bf2f(ov.x); o.y += bf2f(ov.y);
            o.z += bf2f(ov.z); o.w += bf2f(ov.w);
            L.x += lv.x; L.y += lv.y; L.z += lv.z; L.w += lv.w;
        }
        size_t ob = ((size_t)b * 64 + c) * NTOK + nt * 64 + ns;
        float4 xv = *(const float4*)&x[ob];
        float4 res;
        res.x = g * (o.x / L.x) + xv.x;
        res.y = g * (o.y / L.y) + xv.y;
        res.z = g * (o.z / L.z) + xv.z;
        res.w = g * (o.w / L.w) + xv.w;
        *(float4*)&out[ob] = res;
    }
}

extern "C" void kernel_launch(void* const* d_in, const int* in_sizes, int n_in,
                              void* d_out, int out_size, void* d_ws, size_t ws_size,
                              hipStream_t stream) {
    const float* x     = (const float*)d_in[0];
    const float* ctx   = (const float*)d_in[1];
    const float* Wq    = (const float*)d_in[2];
    const float* bq    = (const float*)d_in[3];
    const float* Wk    = (const float*)d_in[4];
    const float* bk    = (const float*)d_in[5];
    const float* Wv    = (const float*)d_in[6];
    const float* bv    = (const float*)d_in[7];
    const float* gamma = (const float*)d_in[8];
    float* out = (float*)d_out;

    char* ws = (char*)d_ws;
    unsigned short* qbf   = (unsigned short*)ws;              // [2][4096][8] bf16 (128 KB)
    unsigned short* kbf   = (unsigned short*)(ws + 131072);   // [2][4096][8] bf16 (128 KB)
    unsigned char*  vtp   = (unsigned char*)(ws + 262144);    // [2][128T][4ct][512] fp8 (512 KB)
    unsigned short* partO = (unsigned short*)(ws + 786432);   // [1024][4096] bf16 (8 MB)
    float*          partL = (float*)(ws + 786432 + (size_t)2 * 64 * 8 * 4096 * 2); // [1024][64]

    proj2<<<dim3(64, 2, 2), 512, 0, stream>>>(x, ctx, Wq, bq, Wk, bk, Wv, bv,
                                              qbf, kbf, vtp);
    attn10<<<dim3(NTOK / 64, 2, 8), 256, 0, stream>>>(qbf, kbf, vtp, partO, partL);
    mergeq<<<dim3(NTOK / 64, 2), 256, 0, stream>>>(partO, partL, x, gamma, out);
}